// Round 3
// baseline (198.366 us; speedup 1.0000x reference)
//
#include <hip/hip_runtime.h>

// Reference analysis: out = ((v0*DECAY + s) * (1 - ((v0*DECAY + s) > T)) > T)
// is identically 0 for all inputs (incl. NaN): if v > T the reset zeroes v
// (0 > 0.5 false); if v <= T the strict compare fails. Pure zero-fill of
// d_out (32*4096*256 fp32 = 128 MiB). Write-only HBM-bound; measured fill
// ceiling on this box is ~6.7 TB/s -> ~20 us floor for 134 MB.
//
// 4x 16B nontemporal stores per thread (64 B/thread); native clang vector
// type because __builtin_nontemporal_store rejects HIP_vector_type wrappers.

typedef float vfloat4 __attribute__((ext_vector_type(4)));

__global__ void __launch_bounds__(256) OutputLayer_3100966388047_kernel(
        vfloat4* __restrict__ out, int n4) {
    const vfloat4 z = {0.0f, 0.0f, 0.0f, 0.0f};
    // Each block covers 256*4 = 1024 consecutive 16B chunks, coalesced per pass.
    int base = blockIdx.x * (blockDim.x * 4) + threadIdx.x;
#pragma unroll
    for (int k = 0; k < 4; ++k) {
        int i = base + k * 256;
        if (i < n4) {
            __builtin_nontemporal_store(z, &out[i]);
        }
    }
}

extern "C" void kernel_launch(void* const* d_in, const int* in_sizes, int n_in,
                              void* d_out, int out_size, void* d_ws, size_t ws_size,
                              hipStream_t stream) {
    (void)d_in; (void)in_sizes; (void)n_in; (void)d_ws; (void)ws_size;
    int n4 = out_size / 4;                 // 8,388,608 16B chunks
    const int block = 256;
    const int per_block = block * 4;       // 1024 chunks per block
    int grid = (n4 + per_block - 1) / per_block;  // 8192 blocks = 32/CU
    OutputLayer_3100966388047_kernel<<<grid, block, 0, stream>>>((vfloat4*)d_out, n4);
}